// Round 2
// baseline (586.677 us; speedup 1.0000x reference)
//
#include <hip/hip_runtime.h>
#include <math.h>

#define NJ   17
#define NCA  272
#define NC   512
#define NHW  3136
#define NB   64

// Nonzero structure of the 17x17 ADJ matrix (row-compressed), derived from the
// reference's ADJ constant. ROW_PTR[r]..ROW_PTR[r+1] index into NZ_COL / e.
__constant__ int ROW_PTR[18] = {0,2,5,8,11,14,16,20,23,28,30,32,35,38,41,44,46,49};
__constant__ int NZ_COL[49] = {
  0,1,            // row 0
  0,1,2,          // row 1
  1,2,6,          // row 2
  3,4,6,          // row 3
  3,4,5,          // row 4
  4,5,            // row 5
  2,3,6,7,        // row 6
  6,7,8,          // row 7
  7,8,11,12,16,   // row 8
  9,16,           // row 9
  10,11,          // row 10
  10,11,12,       // row 11
  8,11,12,        // row 12
  8,13,14,        // row 13
  13,14,15,       // row 14
  14,15,          // row 15
  8,9,16          // row 16
};

// ---------------- Kernel 1: spatial mean of x -> xm[n*NC+c] ----------------
// One WAVE per (n,c) plane; 4 independent waves per block, no LDS, no syncs.
// 3136 floats = 784 float4 = 12*64 + 16.
__global__ __launch_bounds__(256) void spatial_mean_k(const float* __restrict__ x,
                                                      float* __restrict__ xm) {
    const int wv = threadIdx.x >> 6, lane = threadIdx.x & 63;
    const int nc = blockIdx.x * 4 + wv;
    const float4* p = reinterpret_cast<const float4*>(x) + (size_t)nc * (NHW / 4);
    float s = 0.f;
    #pragma unroll
    for (int i = 0; i < 12; ++i) {               // 12 outstanding float4 loads
        float4 v = p[lane + 64 * i];
        s += (v.x + v.y) + (v.z + v.w);
    }
    if (lane < 16) {                              // tail: 784 - 768 = 16
        float4 v = p[768 + lane];
        s += (v.x + v.y) + (v.z + v.w);
    }
    #pragma unroll
    for (int off = 32; off > 0; off >>= 1) s += __shfl_down(s, off, 64);
    if (lane == 0) xm[nc] = s * (1.0f / NHW);
}

// ---------------- Kernel 2: all the tiny dense algebra ----------------
// One block per batch element n. xm lives in d_out (same 64*512 shape) and is
// overwritten in place: block n reads its slice into LDS before writing it.
__global__ __launch_bounds__(256) void head_k(const float* __restrict__ e,
                                              const float* __restrict__ w1,
                                              const float* __restrict__ w2,
                                              const float* __restrict__ fc1,
                                              const float* __restrict__ fc2,
                                              float* __restrict__ out) {
    __shared__ __align__(16) float s_xm[NC];
    __shared__ float s_x1[NCA];
    __shared__ float s_x2[NCA];
    __shared__ float s_f1[NJ];
    __shared__ float s_gc[NJ];
    __shared__ float s_adj[NJ * NJ];

    const int n = blockIdx.x;
    const int t = threadIdx.x;
    const int lane = t & 63, wv = t >> 6;

    for (int i = t; i < NC; i += 256) s_xm[i] = out[n * NC + i];

    // adjacency softmax: thread r (<17) handles row r over its nonzero slots
    if (t < NJ) {
        const int b = ROW_PTR[t], en = ROW_PTR[t + 1];
        float m = -1e30f;
        for (int k = b; k < en; ++k) m = fmaxf(m, e[k]);
        float vals[5];
        float sum = 0.f;
        for (int k = b; k < en; ++k) { float v = expf(e[k] - m); vals[k - b] = v; sum += v; }
        for (int c = 0; c < NJ; ++c) s_adj[t * NJ + c] = 0.f;
        const float inv = 1.f / sum;
        for (int k = b; k < en; ++k) s_adj[t * NJ + NZ_COL[k]] = vals[k - b] * inv;
    }
    __syncthreads();

    // x1[o] = sum_c xm[c] * w1[o,c]   (272 outputs, dot over 512)
    // wave-cooperative: each wave owns outputs o = wv, wv+4, ... ; lanes split c.
    for (int o = wv; o < NCA; o += 4) {
        const float4* wp = reinterpret_cast<const float4*>(w1 + o * NC);
        const float4* xp = reinterpret_cast<const float4*>(s_xm);
        float s = 0.f;
        #pragma unroll
        for (int i = lane; i < NC / 4; i += 64) {   // 2 iterations
            float4 wvv = wp[i];
            float4 xv  = xp[i];
            s += wvv.x * xv.x + wvv.y * xv.y + wvv.z * xv.z + wvv.w * xv.w;
        }
        #pragma unroll
        for (int off = 32; off > 0; off >>= 1) s += __shfl_down(s, off, 64);
        if (lane == 0) s_x1[o] = s;
    }
    __syncthreads();

    // grouped 1x1 conv: x2[g*17+o] = sum_i x1[g*17+i] * w2[(g*17+o), i]
    for (int idx = t; idx < NCA; idx += 256) {
        const int g = idx / NJ, o = idx % NJ;
        const float* wr = w2 + (g * NJ + o) * NJ;
        const float* xr = s_x1 + g * NJ;
        float s = 0.f;
        #pragma unroll
        for (int i = 0; i < NJ; ++i) s += xr[i] * wr[i];
        s_x2[idx] = s;
    }
    __syncthreads();

    // f1[j] = sum_k x2[k] * fc1[j,k]
    if (t < NJ) {
        const float* fr = fc1 + t * NCA;
        float s = 0.f;
        for (int k = 0; k < NCA; ++k) s += s_x2[k] * fr[k];
        s_f1[t] = s;
    }
    __syncthreads();

    // gc[j] = relu( sum_k adj[j,k] * f1[k] )
    if (t < NJ) {
        float s = 0.f;
        #pragma unroll
        for (int k = 0; k < NJ; ++k) s += s_adj[t * NJ + k] * s_f1[k];
        s_gc[t] = fmaxf(s, 0.f);
    }
    __syncthreads();

    // out[c] = sigmoid( sum_j gc[j] * fc2[c,j] )
    for (int c = t; c < NC; c += 256) {
        const float* fr = fc2 + c * NJ;
        float s = 0.f;
        #pragma unroll
        for (int j = 0; j < NJ; ++j) s += s_gc[j] * fr[j];
        out[n * NC + c] = 1.f / (1.f + expf(-s));
    }
}

extern "C" void kernel_launch(void* const* d_in, const int* in_sizes, int n_in,
                              void* d_out, int out_size, void* d_ws, size_t ws_size,
                              hipStream_t stream) {
    const float* x   = (const float*)d_in[0];
    const float* e   = (const float*)d_in[1];
    const float* w1  = (const float*)d_in[2];
    const float* w2  = (const float*)d_in[3];
    const float* fc1 = (const float*)d_in[4];
    const float* fc2 = (const float*)d_in[5];
    float* out = (float*)d_out;

    // Stage means directly in d_out (same 64*512 extent); head_k overwrites
    // it in place (each block consumes its slice before writing it).
    spatial_mean_k<<<(NB * NC) / 4, 256, 0, stream>>>(x, out);
    head_k<<<NB, 256, 0, stream>>>(e, w1, w2, fc1, fc2, out);
}

// Round 4
// 554.743 us; speedup vs baseline: 1.0576x; 1.0576x over previous
//
#include <hip/hip_runtime.h>
#include <math.h>

#define NJ   17
#define NCA  272
#define NC   512
#define NHW  3136
#define NB   64

typedef float vfloat4 __attribute__((ext_vector_type(4)));  // clang-native for nt loads

// Nonzero structure of the 17x17 ADJ matrix (row-compressed), derived from the
// reference's ADJ constant. ROW_PTR[r]..ROW_PTR[r+1] index into NZ_COL / e.
__constant__ int ROW_PTR[18] = {0,2,5,8,11,14,16,20,23,28,30,32,35,38,41,44,46,49};
__constant__ int NZ_COL[49] = {
  0,1,            // row 0
  0,1,2,          // row 1
  1,2,6,          // row 2
  3,4,6,          // row 3
  3,4,5,          // row 4
  4,5,            // row 5
  2,3,6,7,        // row 6
  6,7,8,          // row 7
  7,8,11,12,16,   // row 8
  9,16,           // row 9
  10,11,          // row 10
  10,11,12,       // row 11
  8,11,12,        // row 12
  8,13,14,        // row 13
  13,14,15,       // row 14
  14,15,          // row 15
  8,9,16          // row 16
};

// ---------------- Kernel 1: spatial mean of x -> xm[n*NC+c] ----------------
// Each wave owns 4 consecutive (n,c) planes; each 16-lane group owns one
// plane (784 float4 / 16 lanes = 49 fully-active nt loads, zero tail).
__global__ __launch_bounds__(256) void spatial_mean_k(const float* __restrict__ x,
                                                      float* __restrict__ xm) {
    const int wv   = threadIdx.x >> 6, lane = threadIdx.x & 63;
    const int sub  = lane >> 4;               // which of the 4 planes
    const int sl   = lane & 15;               // sublane within the 16-group
    const int nc0  = (blockIdx.x * 4 + wv) * 4;
    const vfloat4* p = reinterpret_cast<const vfloat4*>(x)
                     + (size_t)(nc0 + sub) * (NHW / 4);
    float s = 0.f;
    #pragma unroll 7
    for (int i = 0; i < 49; ++i) {            // 49 * 16 = 784 float4 = one plane
        vfloat4 v = __builtin_nontemporal_load(&p[sl + 16 * i]);
        s += (v.x + v.y) + (v.z + v.w);
    }
    s += __shfl_down(s, 8, 64);
    s += __shfl_down(s, 4, 64);
    s += __shfl_down(s, 2, 64);
    s += __shfl_down(s, 1, 64);
    if (sl == 0) xm[nc0 + sub] = s * (1.0f / NHW);
}

// ---------------- Kernel 2: all the tiny dense algebra ----------------
// One block per batch element n. xm lives in d_out (same 64*512 shape) and is
// overwritten in place: block n reads its slice into LDS before writing it.
__global__ __launch_bounds__(256) void head_k(const float* __restrict__ e,
                                              const float* __restrict__ w1,
                                              const float* __restrict__ w2,
                                              const float* __restrict__ fc1,
                                              const float* __restrict__ fc2,
                                              float* __restrict__ out) {
    __shared__ __align__(16) float s_xm[NC];
    __shared__ float s_x1[NCA];
    __shared__ float s_x2[NCA];
    __shared__ float s_f1[NJ];
    __shared__ float s_gc[NJ];
    __shared__ float s_adj[NJ * NJ];

    const int n = blockIdx.x;
    const int t = threadIdx.x;
    const int lane = t & 63, wv = t >> 6;

    for (int i = t; i < NC; i += 256) s_xm[i] = out[n * NC + i];

    // adjacency softmax: thread r (<17) handles row r over its nonzero slots
    if (t < NJ) {
        const int b = ROW_PTR[t], en = ROW_PTR[t + 1];
        float m = -1e30f;
        for (int k = b; k < en; ++k) m = fmaxf(m, e[k]);
        float vals[5];
        float sum = 0.f;
        for (int k = b; k < en; ++k) { float v = expf(e[k] - m); vals[k - b] = v; sum += v; }
        for (int c = 0; c < NJ; ++c) s_adj[t * NJ + c] = 0.f;
        const float inv = 1.f / sum;
        for (int k = b; k < en; ++k) s_adj[t * NJ + NZ_COL[k]] = vals[k - b] * inv;
    }
    __syncthreads();

    // x1[o] = sum_c xm[c] * w1[o,c]   (272 outputs, dot over 512)
    for (int o = wv; o < NCA; o += 4) {
        const float4* wp = reinterpret_cast<const float4*>(w1 + o * NC);
        const float4* xp = reinterpret_cast<const float4*>(s_xm);
        float s = 0.f;
        #pragma unroll
        for (int i = lane; i < NC / 4; i += 64) {   // 2 iterations
            float4 wvv = wp[i];
            float4 xv  = xp[i];
            s += wvv.x * xv.x + wvv.y * xv.y + wvv.z * xv.z + wvv.w * xv.w;
        }
        #pragma unroll
        for (int off = 32; off > 0; off >>= 1) s += __shfl_down(s, off, 64);
        if (lane == 0) s_x1[o] = s;
    }
    __syncthreads();

    // grouped 1x1 conv: x2[g*17+o] = sum_i x1[g*17+i] * w2[(g*17+o), i]
    for (int idx = t; idx < NCA; idx += 256) {
        const int g = idx / NJ, o = idx % NJ;
        const float* wr = w2 + (g * NJ + o) * NJ;
        const float* xr = s_x1 + g * NJ;
        float s = 0.f;
        #pragma unroll
        for (int i = 0; i < NJ; ++i) s += xr[i] * wr[i];
        s_x2[idx] = s;
    }
    __syncthreads();

    // f1[j] = sum_k x2[k] * fc1[j,k]
    if (t < NJ) {
        const float* fr = fc1 + t * NCA;
        float s = 0.f;
        for (int k = 0; k < NCA; ++k) s += s_x2[k] * fr[k];
        s_f1[t] = s;
    }
    __syncthreads();

    // gc[j] = relu( sum_k adj[j,k] * f1[k] )
    if (t < NJ) {
        float s = 0.f;
        #pragma unroll
        for (int k = 0; k < NJ; ++k) s += s_adj[t * NJ + k] * s_f1[k];
        s_gc[t] = fmaxf(s, 0.f);
    }
    __syncthreads();

    // out[c] = sigmoid( sum_j gc[j] * fc2[c,j] )
    for (int c = t; c < NC; c += 256) {
        const float* fr = fc2 + c * NJ;
        float s = 0.f;
        #pragma unroll
        for (int j = 0; j < NJ; ++j) s += s_gc[j] * fr[j];
        out[n * NC + c] = 1.f / (1.f + expf(-s));
    }
}

extern "C" void kernel_launch(void* const* d_in, const int* in_sizes, int n_in,
                              void* d_out, int out_size, void* d_ws, size_t ws_size,
                              hipStream_t stream) {
    const float* x   = (const float*)d_in[0];
    const float* e   = (const float*)d_in[1];
    const float* w1  = (const float*)d_in[2];
    const float* w2  = (const float*)d_in[3];
    const float* fc1 = (const float*)d_in[4];
    const float* fc2 = (const float*)d_in[5];
    float* out = (float*)d_out;

    // Stage means directly in d_out (same 64*512 extent); head_k overwrites
    // it in place (each block consumes its slice before writing it).
    spatial_mean_k<<<(NB * NC) / 16, 256, 0, stream>>>(x, out);
    head_k<<<NB, 256, 0, stream>>>(e, w1, w2, fc1, fc2, out);
}